// Round 1
// baseline (140.911 us; speedup 1.0000x reference)
//
#include <hip/hip_runtime.h>

// FullRelPos: out[b,q,g, kh*32+kw] = attn[...] + lh[b,q,g,kh] + lw[b,q,g,kw]
//   lh[k] = sum_c q[b,q,g,c]    * rel_emb_h[(k - h + 31)*32 + c]
//   lw[k] = sum_c q[b,q,g,32+c] * rel_emb_w[(k - w + 31)*32 + c]
// with q = (h,w) grid position: h = hw>>5, w = hw&31, hw = query index.
//
// Memory-bound: 256MB attn read + 256MB out write + 16MB q read.
// One wave (64 lanes) per row; logits in registers; shfl redistribute; float4 stream.

#define HH 32
#define WW 32
#define CC 32      // DIM/2
#define QL 1024    // H*W

__global__ __launch_bounds__(256) void relpos_stream_kernel(
    const float* __restrict__ q,
    const float* __restrict__ attn,
    const float* __restrict__ reh,
    const float* __restrict__ rew,
    float* __restrict__ out,
    int nrows)
{
    const int lane = threadIdx.x & 63;
    const int wid  = blockIdx.x * 4 + (threadIdx.x >> 6);
    const int nwaves = gridDim.x * 4;

    for (int r = wid; r < nrows; r += nwaves) {
        const int hw = (r >> 3) & (QL - 1);  // row order is (b, hw, g); G=8
        const int h  = hw >> 5;
        const int w  = hw & 31;

        // ---- compute logits: lanes 0..31 -> lh[k], lanes 32..63 -> lw[k] ----
        const int k = lane & 31;
        const float* erow = (lane < 32)
            ? (reh + (size_t)(k - h + HH - 1) * CC)
            : (rew + (size_t)(k - w + WW - 1) * CC);
        const float4* e4 = (const float4*)erow;
        // lanes 0..31 use q[0:32] (broadcast), lanes 32..63 use q[32:64]
        const float4* q4 = (const float4*)(q + (size_t)r * 64 + (lane & 32));
        float acc = 0.f;
        #pragma unroll
        for (int c4 = 0; c4 < 8; ++c4) {
            float4 qv = q4[c4];
            float4 ev = e4[c4];
            acc += qv.x * ev.x + qv.y * ev.y + qv.z * ev.z + qv.w * ev.w;
        }

        // ---- redistribute via wave64 shuffles ----
        // lane handles float4 units u = lane + 64*j, j=0..3 (256 units/row)
        //   kh(u) = u/8 = lane/8 + 8j ; kw0(u) = (4u)&31 = (4*lane)&31 (j-invariant)
        const int kw0 = (lane << 2) & 31;
        const float lw0 = __shfl(acc, 32 + kw0,     64);
        const float lw1 = __shfl(acc, 32 + kw0 + 1, 64);
        const float lw2 = __shfl(acc, 32 + kw0 + 2, 64);
        const float lw3 = __shfl(acc, 32 + kw0 + 3, 64);
        const int kh0 = lane >> 3;
        float lhv[4];
        lhv[0] = __shfl(acc, kh0,      64);
        lhv[1] = __shfl(acc, kh0 + 8,  64);
        lhv[2] = __shfl(acc, kh0 + 16, 64);
        lhv[3] = __shfl(acc, kh0 + 24, 64);

        // ---- stream the 4KB row: attn + lh + lw -> out ----
        const float4* arow = (const float4*)(attn + (size_t)r * QL);
        float4*       orow = (float4*)(out + (size_t)r * QL);
        #pragma unroll
        for (int j = 0; j < 4; ++j) {
            float4 a = arow[lane + 64 * j];
            const float t = lhv[j];
            float4 o;
            o.x = a.x + t + lw0;
            o.y = a.y + t + lw1;
            o.z = a.z + t + lw2;
            o.w = a.w + t + lw3;
            orow[lane + 64 * j] = o;
        }
    }
}

extern "C" void kernel_launch(void* const* d_in, const int* in_sizes, int n_in,
                              void* d_out, int out_size, void* d_ws, size_t ws_size,
                              hipStream_t stream) {
    const float* q    = (const float*)d_in[0];
    const float* attn = (const float*)d_in[1];
    const float* reh  = (const float*)d_in[2];
    const float* rew  = (const float*)d_in[3];
    float* out = (float*)d_out;

    const int nrows = in_sizes[1] / QL;  // B * QL * G = 65536
    const int blocks = 2048;             // 8192 waves, grid-stride over rows
    relpos_stream_kernel<<<blocks, 256, 0, stream>>>(q, attn, reh, rew, out, nrows);
}

// Round 2
// 126.577 us; speedup vs baseline: 1.1132x; 1.1132x over previous
//
#include <hip/hip_runtime.h>

// FullRelPos: out[b,hw,g, kh*32+kw] = attn[...] + lh[kh] + lw[kw]
//   lh[k] = dot(q[b,hw,g, 0:32],  rel_emb_h[k-h+31, :])
//   lw[k] = dot(q[b,hw,g,32:64],  rel_emb_w[k-w+31, :])
//
// Memory-bound (256MB attn read + 256MB out write + 16MB q). R0 showed 2.6 TB/s,
// latency-bound: per-row serial chain (q load -> 32-deep FMA -> shfl -> stream).
// Rows (b,hw,g) are contiguous in g: 8 consecutive rows share (h,w) => same emb
// rows. One wave per (b,hw) task: emb loaded once, 8 independent acc chains,
// fully unrolled g-stream so loads of g+1 overlap stores of g.

#define QL 1024    // H*W

__global__ __launch_bounds__(256) void relpos_stream_kernel(
    const float* __restrict__ q,
    const float* __restrict__ attn,
    const float* __restrict__ reh,
    const float* __restrict__ rew,
    float* __restrict__ out,
    int ntasks)
{
    const int lane = threadIdx.x & 63;
    const int wid  = blockIdx.x * 4 + (threadIdx.x >> 6);
    const int nwaves = gridDim.x * 4;

    for (int t = wid; t < ntasks; t += nwaves) {
        const int hw = t & (QL - 1);         // task order is (b, hw); G=8 rows per task
        const int h  = hw >> 5;
        const int w  = hw & 31;
        const size_t r0 = (size_t)t << 3;    // first of 8 contiguous rows (g=0..7)

        // lanes 0..31 own lh[k], lanes 32..63 own lw[k] (k = lane&31)
        const int k = lane & 31;
        const float4* e4 = (lane < 32)
            ? (const float4*)(reh + (size_t)(k - h + 31) * 32)
            : (const float4*)(rew + (size_t)(k - w + 31) * 32);
        const float* qbase = q + r0 * 64 + (lane & 32);  // broadcast per half-wave

        // ---- 8 independent dot-product chains, emb loaded once per c4 ----
        float acc[8];
        #pragma unroll
        for (int g = 0; g < 8; ++g) acc[g] = 0.f;

        #pragma unroll
        for (int c4 = 0; c4 < 8; ++c4) {
            const float4 ev = e4[c4];
            #pragma unroll
            for (int g = 0; g < 8; ++g) {
                const float4 qv = *(const float4*)(qbase + g * 64 + c4 * 4);
                acc[g] += qv.x * ev.x + qv.y * ev.y + qv.z * ev.z + qv.w * ev.w;
            }
        }

        // ---- per g: redistribute via wave64 shuffles, stream the 4KB row ----
        // lane's float4 units u = lane + 64*j: kh(u) = lane/8 + 8j, kw0 = (4*lane)&31
        const int kw0 = (lane << 2) & 31;
        const int kh0 = lane >> 3;
        #pragma unroll
        for (int g = 0; g < 8; ++g) {
            const float a = acc[g];
            const float lw0 = __shfl(a, 32 + kw0,     64);
            const float lw1 = __shfl(a, 32 + kw0 + 1, 64);
            const float lw2 = __shfl(a, 32 + kw0 + 2, 64);
            const float lw3 = __shfl(a, 32 + kw0 + 3, 64);
            float lhv[4];
            lhv[0] = __shfl(a, kh0,      64);
            lhv[1] = __shfl(a, kh0 + 8,  64);
            lhv[2] = __shfl(a, kh0 + 16, 64);
            lhv[3] = __shfl(a, kh0 + 24, 64);

            const float4* arow = (const float4*)(attn + (r0 + g) * QL);
            float4*       orow = (float4*)(out  + (r0 + g) * QL);
            #pragma unroll
            for (int j = 0; j < 4; ++j) {
                float4 av = arow[lane + 64 * j];
                const float tl = lhv[j];
                float4 o;
                o.x = av.x + tl + lw0;
                o.y = av.y + tl + lw1;
                o.z = av.z + tl + lw2;
                o.w = av.w + tl + lw3;
                orow[lane + 64 * j] = o;
            }
        }
    }
}

extern "C" void kernel_launch(void* const* d_in, const int* in_sizes, int n_in,
                              void* d_out, int out_size, void* d_ws, size_t ws_size,
                              hipStream_t stream) {
    const float* q    = (const float*)d_in[0];
    const float* attn = (const float*)d_in[1];
    const float* reh  = (const float*)d_in[2];
    const float* rew  = (const float*)d_in[3];
    float* out = (float*)d_out;

    const int nrows  = in_sizes[1] / QL;   // B * QL * G = 65536
    const int ntasks = nrows >> 3;         // one task per (b, hw) = 8192
    const int blocks = 2048;               // 8192 waves -> 1 task per wave
    relpos_stream_kernel<<<blocks, 256, 0, stream>>>(q, attn, reh, rew, out, ntasks);
}